// Round 13
// baseline (242.029 us; speedup 1.0000x reference)
//
#include <hip/hip_runtime.h>

typedef float v2f __attribute__((ext_vector_type(2)));

#define W 1024
#define H 1024
#define NB 16
#define TX 32
#define TY 24               // output rows per block
#define HR 30               // h-conv rows per block = TY + 6
#define NTH 256
#define YBLK ((H + TY - 1) / TY)   // 43 (last block 8 rows OOB, guarded)
#define CPSTRIDE 64         // dwords per channel-pair segment: 32 cols x 2
#define RSTRIDE 260         // dwords per h-row: 4 cp x 64 + 4 pad (bank spread)
// hbuf layout: [row][cp][col][2] + 4-dword row pad.
//   write b128 granule bank-group = (br + 2c) mod 8  -> perfectly balanced
//   read  b64 bank-pair           = (2tx + c) mod 16 -> 2-way (free)

// forced packed-FP32 FMA (VOP3P, all operands are VGPR pairs — proven to
// assemble in r10; only Stage C uses it, so register pinning stays light).
__device__ __forceinline__ v2f pk_fma(v2f a, v2f b, v2f c) {
    v2f d; asm("v_pk_fma_f32 %0, %1, %2, %3" : "=v"(d) : "v"(a), "v"(b), "v"(c)); return d;
}

// Fused SSIM: Stage B scalar 7-tap horizontal conv (no pair-table padding),
// pair-interleaved LDS, Stage C packed vertical conv + SSIM map.
__global__ __launch_bounds__(NTH, 5) void ssim_main(
    const float* __restrict__ img1, const float* __restrict__ img2,
    const float* __restrict__ img3, const float* __restrict__ win,
    float* __restrict__ partial)
{
    __shared__ __align__(16) float hbuf[HR * RSTRIDE];  // 31200 B -> 5 blocks/CU

    const int tid = threadIdx.x;
    const int x0  = blockIdx.x * TX;
    const int ys0 = blockIdx.y * TY;
    const size_t imoff = (size_t)blockIdx.z * (size_t)(W * H);
    const float* p1 = img1 + imoff;
    const float* p2 = img2 + imoff;
    const float* p3 = img3 + imoff;

    // Separable 1-D gaussian: g[j] = win[3][j] / sqrt(win[3][3])
    float g[7];
    {
        const float inv = 1.0f / sqrtf(win[24]);
        #pragma unroll
        for (int j = 0; j < 7; ++j) g[j] = win[21 + j] * inv;
    }

    // ---- Stage B: horizontal conv, global -> LDS (240 tasks) ----
    if (tid < HR * 8) {
        const int br  = tid >> 3;            // 0..29  h-row within block
        const int bc0 = (tid & 7) << 2;      // 0,4,...,28
        const int gy  = ys0 + br - 3;
        const int gx0 = x0 + bc0 - 4;
        const bool xfast = (gx0 >= 0) & (gx0 + 12 <= W);

        float acc[8][4];
        #pragma unroll
        for (int ch = 0; ch < 8; ++ch)
            #pragma unroll
            for (int j = 0; j < 4; ++j) acc[ch][j] = 0.0f;

        if ((gy >= 0) & (gy < H)) {
            const size_t rowoff = (size_t)gy * W;
            float V1[12], V2[12], V3[12];
            if (xfast) {
                const float* q1 = p1 + rowoff + gx0;
                const float* q2 = p2 + rowoff + gx0;
                const float* q3 = p3 + rowoff + gx0;
                *(float4*)&V1[0] = *(const float4*)(q1);
                *(float4*)&V1[4] = *(const float4*)(q1 + 4);
                *(float4*)&V1[8] = *(const float4*)(q1 + 8);
                *(float4*)&V2[0] = *(const float4*)(q2);
                *(float4*)&V2[4] = *(const float4*)(q2 + 4);
                *(float4*)&V2[8] = *(const float4*)(q2 + 8);
                *(float4*)&V3[0] = *(const float4*)(q3);
                *(float4*)&V3[4] = *(const float4*)(q3 + 4);
                *(float4*)&V3[8] = *(const float4*)(q3 + 8);
            } else {
                #pragma unroll
                for (int c = 0; c < 12; ++c) {
                    const int x = gx0 + c;
                    const bool ok = (x >= 0) & (x < W);
                    const size_t off = rowoff + x;
                    V1[c] = ok ? p1[off] : 0.0f;
                    V2[c] = ok ? p2[off] : 0.0f;
                    V3[c] = ok ? p3[off] : 0.0f;
                }
            }
            #pragma unroll
            for (int j = 0; j < 4; ++j) {
                #pragma unroll
                for (int dx = 0; dx < 7; ++dx) {
                    const float w  = g[dx];
                    const float v1 = V1[1 + j + dx];
                    const float v2 = V2[1 + j + dx];
                    const float v3 = V3[1 + j + dx];
                    const float t1 = w * v1;
                    const float t2 = w * v2;
                    const float t3 = w * v3;
                    acc[0][j] += t1;
                    acc[1][j] += t2;
                    acc[2][j] += t3;
                    acc[3][j] += t1 * v1;
                    acc[4][j] += t2 * v2;
                    acc[5][j] += t3 * v3;
                    acc[6][j] += t1 * v2;
                    acc[7][j] += t1 * v3;
                }
            }
        }
        // pair-interleaved write: 2x ds_write_b128 per channel-pair
        const int wbase = br * RSTRIDE + bc0 * 2;
        #pragma unroll
        for (int cp = 0; cp < 4; ++cp) {
            float* d = &hbuf[wbase + cp * CPSTRIDE];
            *(float4*)(d + 0) = make_float4(acc[2 * cp][0], acc[2 * cp + 1][0],
                                            acc[2 * cp][1], acc[2 * cp + 1][1]);
            *(float4*)(d + 4) = make_float4(acc[2 * cp][2], acc[2 * cp + 1][2],
                                            acc[2 * cp][3], acc[2 * cp + 1][3]);
        }
    }
    __syncthreads();

    // ---- Stage C: packed vertical conv (uniform 3-tall) + SSIM ----
    const int tx  = tid & 31;
    const int r0  = (tid >> 5) * 3;          // 0,3,...,21
    float lsum = 0.0f;
    {
        v2f gb[7];
        #pragma unroll
        for (int d = 0; d < 7; ++d) { gb[d].x = g[d]; gb[d].y = g[d]; }

        v2f sv[4][3];
        #pragma unroll
        for (int cp = 0; cp < 4; ++cp)
            #pragma unroll
            for (int j = 0; j < 3; ++j) sv[cp][j] = (v2f)0.0f;

        int base = r0 * RSTRIDE + tx * 2;
        #pragma unroll
        for (int dy = 0; dy < 9; ++dy) {
            v2f p[4];
            #pragma unroll
            for (int cp = 0; cp < 4; ++cp)
                p[cp] = *(const v2f*)&hbuf[base + cp * CPSTRIDE];
            #pragma unroll
            for (int j = 0; j < 3; ++j) {
                const int dd = dy - j;
                if (dd >= 0 && dd < 7) {
                    #pragma unroll
                    for (int cp = 0; cp < 4; ++cp)
                        sv[cp][j] = pk_fma(p[cp], gb[dd], sv[cp][j]);
                }
            }
            base += RSTRIDE;
        }

        #pragma unroll
        for (int j = 0; j < 3; ++j) {
            if (ys0 + r0 + j < H) {
                const float mu1 = sv[0][j].x, mu2 = sv[0][j].y;
                const float mu3 = sv[1][j].x, E11 = sv[1][j].y;
                const float E22 = sv[2][j].x, E33 = sv[2][j].y;
                const float E12 = sv[3][j].x, E13 = sv[3][j].y;
                const float sig1  = E11 - mu1 * mu1;
                const float sig2  = E22 - mu2 * mu2;
                const float sig3  = E33 - mu3 * mu3;
                const float sig12 = E12 - mu1 * mu2;
                const float sig13 = E13 - mu1 * mu3;
                const float C2 = 9.0e-4f;  // 0.03^2
                const float m12 = (2.0f * sig12 + C2) * __builtin_amdgcn_rcpf(sig1 + sig2 + C2);
                const float m13 = (2.0f * sig13 + C2) * __builtin_amdgcn_rcpf(sig1 + sig3 + C2);
                lsum += (mu2 > mu3) ? m12 : m13;
            }
        }
    }

    // ---- Block reduction (deterministic); alias wavesum onto hbuf ----
    #pragma unroll
    for (int o = 32; o > 0; o >>= 1) lsum += __shfl_down(lsum, o, 64);
    __syncthreads();                      // all hbuf reads done before aliasing
    float* wavesum = hbuf;
    if ((tid & 63) == 0) wavesum[tid >> 6] = lsum;
    __syncthreads();
    if (tid == 0) {
        const float t = (wavesum[0] + wavesum[1]) + (wavesum[2] + wavesum[3]);
        partial[((size_t)blockIdx.z * gridDim.y + blockIdx.y) * gridDim.x + blockIdx.x] = t;
    }
}

// Deterministic final reduction: one block, fixed summation order, f64 accum.
__global__ __launch_bounds__(256) void ssim_reduce(
    const float* __restrict__ partial, float* __restrict__ out, int n)
{
    __shared__ double sh[256];
    const int tid = threadIdx.x;
    double s = 0.0;
    for (int i = tid; i < n; i += 256) s += (double)partial[i];
    sh[tid] = s;
    __syncthreads();
    for (int o = 128; o > 0; o >>= 1) {
        if (tid < o) sh[tid] += sh[tid + o];
        __syncthreads();
    }
    if (tid == 0) out[0] = (float)(sh[0] / (double)((size_t)NB * W * H));
}

extern "C" void kernel_launch(void* const* d_in, const int* in_sizes, int n_in,
                              void* d_out, int out_size, void* d_ws, size_t ws_size,
                              hipStream_t stream) {
    const float* img1 = (const float*)d_in[0];
    const float* img2 = (const float*)d_in[1];
    const float* img3 = (const float*)d_in[2];
    const float* win  = (const float*)d_in[3];
    float* out = (float*)d_out;
    float* partial = (float*)d_ws;

    dim3 grid(W / TX, YBLK, NB);  // 32 x 43 x 16 = 22016 blocks
    ssim_main<<<grid, NTH, 0, stream>>>(img1, img2, img3, win, partial);

    const int nblk = (W / TX) * YBLK * NB;
    ssim_reduce<<<1, 256, 0, stream>>>(partial, out, nblk);
}

// Round 14
// 140.900 us; speedup vs baseline: 1.7177x; 1.7177x over previous
//
#include <hip/hip_runtime.h>

typedef float v2f __attribute__((ext_vector_type(2)));

#define W 1024
#define H 1024
#define NB 16
#define TX 32
#define TY 18
#define HR 24               // TY + 6 h-conv rows per block
#define NTH 192             // 3 waves
#define YBLK ((H + TY - 1) / TY)   // 57 (last block 2 rows OOB, guarded)
#define RSTRIDE (8 * TX)    // dwords per h-row: 8 channels x 32 cols

// Fused SSIM (r6 structure, per-m product-hoisted Stage B).
//   hbuf layout: [HR][8 channels][TX] floats (measured conflict-free).
//   Stage B: 192 tasks = 24 rows x 8 col-groups, one per thread.
//            Per window column m: 5 products once, then 8 FMA per valid j.
//            274 conv ops/task (was 308).
//   Stage C: 32 cols x 6 rowgroups x 3-tall vertical conv + SSIM map.
__global__ __launch_bounds__(NTH, 4) void ssim_main(
    const float* __restrict__ img1, const float* __restrict__ img2,
    const float* __restrict__ img3, const float* __restrict__ win,
    float* __restrict__ partial)
{
    __shared__ __align__(16) float hbuf[HR * RSTRIDE];  // 24576 B
    __shared__ float wavesum[3];

    const int tid = threadIdx.x;
    const int x0  = blockIdx.x * TX;
    const int ys0 = blockIdx.y * TY;
    const size_t imoff = (size_t)blockIdx.z * (size_t)(W * H);
    const float* p1 = img1 + imoff;
    const float* p2 = img2 + imoff;
    const float* p3 = img3 + imoff;

    // Separable 1-D gaussian: g[j] = win[3][j] / sqrt(win[3][3])
    float g[7];
    {
        const float inv = 1.0f / sqrtf(win[24]);
        #pragma unroll
        for (int j = 0; j < 7; ++j) g[j] = win[21 + j] * inv;
    }

    // ---- Stage B: horizontal conv, global -> LDS (1 task per thread) ----
    {
        const int br  = tid >> 3;            // 0..23  h-row within block
        const int bc0 = (tid & 7) << 2;      // 0,4,...,28
        const int gy  = ys0 + br - 3;
        const int gx0 = x0 + bc0 - 4;
        const bool xfast = (gx0 >= 0) & (gx0 + 12 <= W);

        float acc[8][4];
        #pragma unroll
        for (int ch = 0; ch < 8; ++ch)
            #pragma unroll
            for (int j = 0; j < 4; ++j) acc[ch][j] = 0.0f;

        if ((gy >= 0) & (gy < H)) {
            const size_t rowoff = (size_t)gy * W;
            float V1[12], V2[12], V3[12];
            if (xfast) {
                const float* q1 = p1 + rowoff + gx0;
                const float* q2 = p2 + rowoff + gx0;
                const float* q3 = p3 + rowoff + gx0;
                *(float4*)&V1[0] = *(const float4*)(q1);
                *(float4*)&V1[4] = *(const float4*)(q1 + 4);
                *(float4*)&V1[8] = *(const float4*)(q1 + 8);
                *(float4*)&V2[0] = *(const float4*)(q2);
                *(float4*)&V2[4] = *(const float4*)(q2 + 4);
                *(float4*)&V2[8] = *(const float4*)(q2 + 8);
                *(float4*)&V3[0] = *(const float4*)(q3);
                *(float4*)&V3[4] = *(const float4*)(q3 + 4);
                *(float4*)&V3[8] = *(const float4*)(q3 + 8);
            } else {
                #pragma unroll
                for (int c = 0; c < 12; ++c) {
                    const int x = gx0 + c;
                    const bool ok = (x >= 0) & (x < W);
                    const size_t off = rowoff + x;
                    V1[c] = ok ? p1[off] : 0.0f;
                    V2[c] = ok ? p2[off] : 0.0f;
                    V3[c] = ok ? p3[off] : 0.0f;
                }
            }

            // per-m product hoisting: output j covers window cols m = 1+j .. 7+j
            #pragma unroll
            for (int m = 1; m <= 10; ++m) {
                const float v1 = V1[m], v2 = V2[m], v3 = V3[m];
                const float p11 = v1 * v1, p22 = v2 * v2, p33 = v3 * v3;
                const float p12 = v1 * v2, p13 = v1 * v3;
                const int jlo = (m - 7 > 0) ? m - 7 : 0;
                const int jhi = (m - 1 < 3) ? m - 1 : 3;
                #pragma unroll
                for (int j = jlo; j <= jhi; ++j) {
                    const float w = g[m - 1 - j];
                    acc[0][j] += w * v1;
                    acc[1][j] += w * v2;
                    acc[2][j] += w * v3;
                    acc[3][j] += w * p11;
                    acc[4][j] += w * p22;
                    acc[5][j] += w * p33;
                    acc[6][j] += w * p12;
                    acc[7][j] += w * p13;
                }
            }
        }
        const int wbase = br * RSTRIDE + bc0;
        #pragma unroll
        for (int ch = 0; ch < 8; ++ch) {
            v2f a, b;
            a.x = acc[ch][0]; a.y = acc[ch][1];
            b.x = acc[ch][2]; b.y = acc[ch][3];
            *(v2f*)&hbuf[wbase + ch * TX]     = a;
            *(v2f*)&hbuf[wbase + ch * TX + 2] = b;
        }
    }
    __syncthreads();

    // ---- Stage C: vertical conv (3-tall), packed across channel pairs ----
    const int tx = tid & 31;
    const int r0 = (tid >> 5) * 3;        // 0,3,...,15

    v2f sv[4][3];
    #pragma unroll
    for (int cp = 0; cp < 4; ++cp)
        #pragma unroll
        for (int j = 0; j < 3; ++j) sv[cp][j] = (v2f)0.0f;

    int base = r0 * RSTRIDE + tx;
    #pragma unroll
    for (int dy = 0; dy < 9; ++dy) {
        v2f p[4];
        #pragma unroll
        for (int cp = 0; cp < 4; ++cp) {
            p[cp].x = hbuf[base + cp * 64];       // channel 2cp
            p[cp].y = hbuf[base + cp * 64 + 32];  // channel 2cp+1
        }
        #pragma unroll
        for (int j = 0; j < 3; ++j) {
            const int dd = dy - j;
            if (dd >= 0 && dd < 7) {
                const float wg = g[dd];
                #pragma unroll
                for (int cp = 0; cp < 4; ++cp) sv[cp][j] += wg * p[cp];
            }
        }
        base += RSTRIDE;
    }

    float lsum = 0.0f;
    #pragma unroll
    for (int j = 0; j < 3; ++j) {
        if (ys0 + r0 + j < H) {
            const float mu1 = sv[0][j].x, mu2 = sv[0][j].y;
            const float mu3 = sv[1][j].x, E11 = sv[1][j].y;
            const float E22 = sv[2][j].x, E33 = sv[2][j].y;
            const float E12 = sv[3][j].x, E13 = sv[3][j].y;
            const float sig1  = E11 - mu1 * mu1;
            const float sig2  = E22 - mu2 * mu2;
            const float sig3  = E33 - mu3 * mu3;
            const float sig12 = E12 - mu1 * mu2;
            const float sig13 = E13 - mu1 * mu3;
            const float C2 = 9.0e-4f;  // 0.03^2
            const float m12 = (2.0f * sig12 + C2) * __builtin_amdgcn_rcpf(sig1 + sig2 + C2);
            const float m13 = (2.0f * sig13 + C2) * __builtin_amdgcn_rcpf(sig1 + sig3 + C2);
            lsum += (mu2 > mu3) ? m12 : m13;
        }
    }

    // ---- Block reduction (deterministic) ----
    #pragma unroll
    for (int o = 32; o > 0; o >>= 1) lsum += __shfl_down(lsum, o, 64);
    if ((tid & 63) == 0) wavesum[tid >> 6] = lsum;
    __syncthreads();
    if (tid == 0) {
        partial[((size_t)blockIdx.z * gridDim.y + blockIdx.y) * gridDim.x + blockIdx.x] =
            wavesum[0] + wavesum[1] + wavesum[2];
    }
}

// Deterministic final reduction: one block, fixed summation order, f64 accum.
__global__ __launch_bounds__(256) void ssim_reduce(
    const float* __restrict__ partial, float* __restrict__ out, int n)
{
    __shared__ double sh[256];
    const int tid = threadIdx.x;
    double s = 0.0;
    for (int i = tid; i < n; i += 256) s += (double)partial[i];
    sh[tid] = s;
    __syncthreads();
    for (int o = 128; o > 0; o >>= 1) {
        if (tid < o) sh[tid] += sh[tid + o];
        __syncthreads();
    }
    if (tid == 0) out[0] = (float)(sh[0] / (double)((size_t)NB * W * H));
}

extern "C" void kernel_launch(void* const* d_in, const int* in_sizes, int n_in,
                              void* d_out, int out_size, void* d_ws, size_t ws_size,
                              hipStream_t stream) {
    const float* img1 = (const float*)d_in[0];
    const float* img2 = (const float*)d_in[1];
    const float* img3 = (const float*)d_in[2];
    const float* win  = (const float*)d_in[3];
    float* out = (float*)d_out;
    float* partial = (float*)d_ws;

    dim3 grid(W / TX, YBLK, NB);  // 32 x 57 x 16 = 29184 blocks
    ssim_main<<<grid, NTH, 0, stream>>>(img1, img2, img3, win, partial);

    const int nblk = (W / TX) * YBLK * NB;
    ssim_reduce<<<1, 256, 0, stream>>>(partial, out, nblk);
}

// Round 15
// 103.512 us; speedup vs baseline: 2.3382x; 1.3612x over previous
//
#include <hip/hip_runtime.h>

typedef float v2f __attribute__((ext_vector_type(2)));

#define W 1024
#define H 1024
#define NB 16
#define TX 32
#define TY 18
#define HR 24               // TY + 6 h-conv rows per block
#define NTH 192             // 3 waves
#define YBLK ((H + TY - 1) / TY)   // 57 (last block 2 rows OOB, guarded)
#define RSTRIDE (8 * TX)    // dwords per h-row: 8 channels x 32 cols
#define NBLK (32 * YBLK * NB)      // 29184 partials = 114 * 256 exactly
#define NRED1 (NBLK / 256)         // 114 level-1 blocks

// Fused SSIM (r6 structure, verbatim — best measured main kernel: 107 µs).
//   hbuf layout: [HR][8 channels][TX] floats, conflict-free.
//   Stage B: 192 tasks = 24 rows x 8 col-groups, one per thread; weight-pair
//            m-loop (regular schedule — do not reorder, r14 regressed).
//   Stage C: 32 cols x 6 rowgroups x 3-tall vertical conv + SSIM map.
__global__ __launch_bounds__(NTH, 4) void ssim_main(
    const float* __restrict__ img1, const float* __restrict__ img2,
    const float* __restrict__ img3, const float* __restrict__ win,
    float* __restrict__ partial)
{
    __shared__ __align__(16) float hbuf[HR * RSTRIDE];  // 24576 B
    __shared__ float wavesum[3];

    const int tid = threadIdx.x;
    const int x0  = blockIdx.x * TX;
    const int ys0 = blockIdx.y * TY;
    const size_t imoff = (size_t)blockIdx.z * (size_t)(W * H);
    const float* p1 = img1 + imoff;
    const float* p2 = img2 + imoff;
    const float* p3 = img3 + imoff;

    // Separable 1-D gaussian: g[j] = win[3][j] / sqrt(win[3][3])
    float g[7];
    {
        const float inv = 1.0f / sqrtf(win[24]);
        #pragma unroll
        for (int j = 0; j < 7; ++j) g[j] = win[21 + j] * inv;
    }

    // ---- Stage B: horizontal conv, global -> LDS (1 task per thread) ----
    {
        const int br  = tid >> 3;            // 0..23  h-row within block
        const int bc0 = (tid & 7) << 2;      // 0,4,...,28
        const int gy  = ys0 + br - 3;
        const int gx0 = x0 + bc0 - 4;
        const bool xfast = (gx0 >= 0) & (gx0 + 12 <= W);

        v2f accA[8], accB[8];                // j=(0,1) and j=(2,3)
        #pragma unroll
        for (int ch = 0; ch < 8; ++ch) { accA[ch] = (v2f)0.0f; accB[ch] = (v2f)0.0f; }

        if ((gy >= 0) & (gy < H)) {
            const size_t rowoff = (size_t)gy * W;
            float V1[12], V2[12], V3[12];
            if (xfast) {
                const float* q1 = p1 + rowoff + gx0;
                const float* q2 = p2 + rowoff + gx0;
                const float* q3 = p3 + rowoff + gx0;
                *(float4*)&V1[0] = *(const float4*)(q1);
                *(float4*)&V1[4] = *(const float4*)(q1 + 4);
                *(float4*)&V1[8] = *(const float4*)(q1 + 8);
                *(float4*)&V2[0] = *(const float4*)(q2);
                *(float4*)&V2[4] = *(const float4*)(q2 + 4);
                *(float4*)&V2[8] = *(const float4*)(q2 + 8);
                *(float4*)&V3[0] = *(const float4*)(q3);
                *(float4*)&V3[4] = *(const float4*)(q3 + 4);
                *(float4*)&V3[8] = *(const float4*)(q3 + 8);
            } else {
                #pragma unroll
                for (int c = 0; c < 12; ++c) {
                    const int x = gx0 + c;
                    const bool ok = (x >= 0) & (x < W);
                    const size_t off = rowoff + x;
                    V1[c] = ok ? p1[off] : 0.0f;
                    V2[c] = ok ? p2[off] : 0.0f;
                    V3[c] = ok ? p3[off] : 0.0f;
                }
            }

            // weight-pair table: gp[m-1] = {g[m-1], g[m-2]} (edges zero-padded)
            v2f gp[8];
            gp[0] = (v2f){g[0], 0.0f};
            #pragma unroll
            for (int m = 2; m <= 7; ++m) gp[m - 1] = (v2f){g[m - 1], g[m - 2]};
            gp[7] = (v2f){0.0f, g[6]};

            #pragma unroll
            for (int m = 1; m <= 8; ++m) {
                const v2f w = gp[m - 1];
                const float vA1 = V1[m], vA2 = V2[m], vA3 = V3[m];
                const float vB1 = V1[m + 2], vB2 = V2[m + 2], vB3 = V3[m + 2];
                v2f t;
                t = w * vA1;
                accA[0] += t;
                accA[3] += t * vA1;
                accA[6] += t * vA2;
                accA[7] += t * vA3;
                t = w * vA2;
                accA[1] += t;
                accA[4] += t * vA2;
                t = w * vA3;
                accA[2] += t;
                accA[5] += t * vA3;
                t = w * vB1;
                accB[0] += t;
                accB[3] += t * vB1;
                accB[6] += t * vB2;
                accB[7] += t * vB3;
                t = w * vB2;
                accB[1] += t;
                accB[4] += t * vB2;
                t = w * vB3;
                accB[2] += t;
                accB[5] += t * vB3;
            }
        }
        const int wbase = br * RSTRIDE + bc0;
        #pragma unroll
        for (int ch = 0; ch < 8; ++ch) {
            *(v2f*)&hbuf[wbase + ch * TX]     = accA[ch];
            *(v2f*)&hbuf[wbase + ch * TX + 2] = accB[ch];
        }
    }
    __syncthreads();

    // ---- Stage C: vertical conv (3-tall), packed across channel pairs ----
    const int tx = tid & 31;
    const int r0 = (tid >> 5) * 3;        // 0,3,...,15

    v2f sv[4][3];
    #pragma unroll
    for (int cp = 0; cp < 4; ++cp)
        #pragma unroll
        for (int j = 0; j < 3; ++j) sv[cp][j] = (v2f)0.0f;

    int base = r0 * RSTRIDE + tx;
    #pragma unroll
    for (int dy = 0; dy < 9; ++dy) {
        v2f p[4];
        #pragma unroll
        for (int cp = 0; cp < 4; ++cp) {
            p[cp].x = hbuf[base + cp * 64];       // channel 2cp
            p[cp].y = hbuf[base + cp * 64 + 32];  // channel 2cp+1
        }
        #pragma unroll
        for (int j = 0; j < 3; ++j) {
            const int dd = dy - j;
            if (dd >= 0 && dd < 7) {
                const float wg = g[dd];
                #pragma unroll
                for (int cp = 0; cp < 4; ++cp) sv[cp][j] += wg * p[cp];
            }
        }
        base += RSTRIDE;
    }

    float lsum = 0.0f;
    #pragma unroll
    for (int j = 0; j < 3; ++j) {
        if (ys0 + r0 + j < H) {
            const float mu1 = sv[0][j].x, mu2 = sv[0][j].y;
            const float mu3 = sv[1][j].x, E11 = sv[1][j].y;
            const float E22 = sv[2][j].x, E33 = sv[2][j].y;
            const float E12 = sv[3][j].x, E13 = sv[3][j].y;
            const float sig1  = E11 - mu1 * mu1;
            const float sig2  = E22 - mu2 * mu2;
            const float sig3  = E33 - mu3 * mu3;
            const float sig12 = E12 - mu1 * mu2;
            const float sig13 = E13 - mu1 * mu3;
            const float C2 = 9.0e-4f;  // 0.03^2
            const float m12 = (2.0f * sig12 + C2) * __builtin_amdgcn_rcpf(sig1 + sig2 + C2);
            const float m13 = (2.0f * sig13 + C2) * __builtin_amdgcn_rcpf(sig1 + sig3 + C2);
            lsum += (mu2 > mu3) ? m12 : m13;
        }
    }

    // ---- Block reduction (deterministic) ----
    #pragma unroll
    for (int o = 32; o > 0; o >>= 1) lsum += __shfl_down(lsum, o, 64);
    if ((tid & 63) == 0) wavesum[tid >> 6] = lsum;
    __syncthreads();
    if (tid == 0) {
        partial[((size_t)blockIdx.z * gridDim.y + blockIdx.y) * gridDim.x + blockIdx.x] =
            wavesum[0] + wavesum[1] + wavesum[2];
    }
}

// Level-1 reduction: 114 blocks x 256 threads, each reduces exactly 256
// contiguous partials via deterministic LDS f64 tree.
__global__ __launch_bounds__(256) void ssim_reduce1(
    const float* __restrict__ partial, double* __restrict__ p2)
{
    __shared__ double sh[256];
    const int t = threadIdx.x;
    sh[t] = (double)partial[blockIdx.x * 256 + t];
    __syncthreads();
    #pragma unroll
    for (int o = 128; o > 0; o >>= 1) {
        if (t < o) sh[t] += sh[t + o];
        __syncthreads();
    }
    if (t == 0) p2[blockIdx.x] = sh[0];
}

// Level-2: one block sums the 114 doubles (fixed order) and writes the mean.
__global__ __launch_bounds__(128) void ssim_reduce2(
    const double* __restrict__ p2, float* __restrict__ out)
{
    __shared__ double sh[128];
    const int t = threadIdx.x;
    sh[t] = (t < NRED1) ? p2[t] : 0.0;
    __syncthreads();
    #pragma unroll
    for (int o = 64; o > 0; o >>= 1) {
        if (t < o) sh[t] += sh[t + o];
        __syncthreads();
    }
    if (t == 0) out[0] = (float)(sh[0] / (double)((size_t)NB * W * H));
}

extern "C" void kernel_launch(void* const* d_in, const int* in_sizes, int n_in,
                              void* d_out, int out_size, void* d_ws, size_t ws_size,
                              hipStream_t stream) {
    const float* img1 = (const float*)d_in[0];
    const float* img2 = (const float*)d_in[1];
    const float* img3 = (const float*)d_in[2];
    const float* win  = (const float*)d_in[3];
    float* out = (float*)d_out;
    float* partial = (float*)d_ws;                                   // NBLK floats
    double* p2 = (double*)((char*)d_ws + (size_t)NBLK * 4);          // 8B-aligned (NBLK*4 % 8 == 0)

    dim3 grid(W / TX, YBLK, NB);  // 32 x 57 x 16 = 29184 blocks
    ssim_main<<<grid, NTH, 0, stream>>>(img1, img2, img3, win, partial);
    ssim_reduce1<<<NRED1, 256, 0, stream>>>(partial, p2);
    ssim_reduce2<<<1, 128, 0, stream>>>(p2, out);
}